// Round 1
// baseline (1565.236 us; speedup 1.0000x reference)
//
#include <hip/hip_runtime.h>

#define NEG_SLOPE 0.2f

__device__ __forceinline__ float lrelu(float x) { return x > 0.f ? x : NEG_SLOPE * x; }

// ---------------- CSR build ----------------
__global__ void count_kernel(const int* __restrict__ dst, int E, int* __restrict__ counts) {
    int stride = gridDim.x * blockDim.x;
    for (int i = blockIdx.x * blockDim.x + threadIdx.x; i < E; i += stride)
        atomicAdd(&counts[dst[i]], 1);
}

// single-block exclusive scan of (counts[i] + 1)  (+1 = self loop)
__global__ __launch_bounds__(1024) void scan_kernel(const int* __restrict__ counts, int N,
                                                    int* __restrict__ row_ptr, int* __restrict__ cursor) {
    __shared__ int lds[1024];
    __shared__ int s_carry;
    int t = threadIdx.x;
    if (t == 0) s_carry = 0;
    __syncthreads();
    for (int base = 0; base < N; base += 1024) {
        int i = base + t;
        int v = (i < N) ? (counts[i] + 1) : 0;
        lds[t] = v;
        __syncthreads();
        for (int off = 1; off < 1024; off <<= 1) {
            int add = (t >= off) ? lds[t - off] : 0;
            __syncthreads();
            lds[t] += add;
            __syncthreads();
        }
        int incl = lds[t];
        int total = lds[1023];
        int carry = s_carry;
        if (i < N) {
            int excl = carry + incl - v;
            row_ptr[i] = excl;
            cursor[i]  = excl;
        }
        __syncthreads();
        if (t == 0) s_carry = carry + total;
        __syncthreads();
    }
    if (t == 0) row_ptr[N] = s_carry;
}

__global__ void scatter_kernel(const int* __restrict__ src, const int* __restrict__ dst,
                               int E, int N, int* __restrict__ cursor, int* __restrict__ csr_src) {
    int stride = gridDim.x * blockDim.x;
    int total = E + N;
    for (int i = blockIdx.x * blockDim.x + threadIdx.x; i < total; i += stride) {
        int s, d;
        if (i < E) { s = src[i]; d = dst[i]; }
        else       { s = i - E;  d = s; }
        csr_src[atomicAdd(&cursor[d], 1)] = s;
    }
}

// ---------------- layer 0 GEMM:  h0 = x @ W0  [N,128]x[128,256], fused alpha dots ----------------
// block = 256 threads, 64 rows/block; thread t: row r=t>>2, head cg=t&3 (64 cols each)
__global__ __launch_bounds__(256) void gemm0_kernel(
        const float* __restrict__ x, const float* __restrict__ W0,
        const float* __restrict__ a_src, const float* __restrict__ a_dst,
        int N, float* __restrict__ h0, float* __restrict__ alpha_s, float* __restrict__ alpha_d) {
    __shared__ float xs[64][132];   // pad 132: 2-way bank alias only (free)
    int block_row = blockIdx.x * 64;
    int t = threadIdx.x;
    // stage x tile [64][128]
    for (int i = t; i < 64 * 32; i += 256) {
        int r = i >> 5, c4 = i & 31;
        int gr = block_row + r;
        float4 v = (gr < N) ? ((const float4*)x)[(size_t)gr * 32 + c4] : make_float4(0, 0, 0, 0);
        *((float4*)&xs[r][c4 * 4]) = v;
    }
    __syncthreads();
    int r = t >> 2;
    int cg = t & 3;
    float acc[64];
#pragma unroll
    for (int j = 0; j < 64; j++) acc[j] = 0.f;
    const float* wbase = W0 + cg * 64;
    for (int k = 0; k < 128; k++) {
        float xv = xs[r][k];
        const float4* w4 = (const float4*)(wbase + (size_t)k * 256);
#pragma unroll
        for (int j4 = 0; j4 < 16; j4++) {
            float4 w = w4[j4];
            acc[j4 * 4 + 0] += xv * w.x;
            acc[j4 * 4 + 1] += xv * w.y;
            acc[j4 * 4 + 2] += xv * w.z;
            acc[j4 * 4 + 3] += xv * w.w;
        }
    }
    int gr = block_row + r;
    if (gr < N) {
        float4* o4 = (float4*)(h0 + (size_t)gr * 256 + cg * 64);
        float sdot = 0.f, ddot = 0.f;
#pragma unroll
        for (int j4 = 0; j4 < 16; j4++) {
            o4[j4] = make_float4(acc[j4 * 4], acc[j4 * 4 + 1], acc[j4 * 4 + 2], acc[j4 * 4 + 3]);
        }
#pragma unroll
        for (int j = 0; j < 64; j++) {
            sdot += acc[j] * a_src[cg * 64 + j];
            ddot += acc[j] * a_dst[cg * 64 + j];
        }
        alpha_s[(size_t)gr * 4 + cg] = sdot;
        alpha_d[(size_t)gr * 4 + cg] = ddot;
    }
}

// ---------------- layer 0 aggregation: one wave per dst node ----------------
__global__ __launch_bounds__(256) void agg0_kernel(
        const int* __restrict__ row_ptr, const int* __restrict__ csr_src,
        const float* __restrict__ h0, const float* __restrict__ as0, const float* __restrict__ ad0,
        const float* __restrict__ bias0, int N, float* __restrict__ h1) {
    int wid = (blockIdx.x * blockDim.x + threadIdx.x) >> 6;
    int lane = threadIdx.x & 63;
    if (wid >= N) return;
    int beg = row_ptr[wid], end = row_ptr[wid + 1];
    float ad[4];
#pragma unroll
    for (int h = 0; h < 4; h++) ad[h] = ad0[(size_t)wid * 4 + h];

    float m[4] = {-1e30f, -1e30f, -1e30f, -1e30f};
    for (int i = beg + lane; i < end; i += 64) {
        int s = csr_src[i];
#pragma unroll
        for (int h = 0; h < 4; h++) m[h] = fmaxf(m[h], lrelu(as0[(size_t)s * 4 + h] + ad[h]));
    }
#pragma unroll
    for (int off = 32; off; off >>= 1)
#pragma unroll
        for (int h = 0; h < 4; h++) m[h] = fmaxf(m[h], __shfl_xor(m[h], off));

    float ssum[4] = {0.f, 0.f, 0.f, 0.f};
    for (int i = beg + lane; i < end; i += 64) {
        int s = csr_src[i];
#pragma unroll
        for (int h = 0; h < 4; h++) ssum[h] += __expf(lrelu(as0[(size_t)s * 4 + h] + ad[h]) - m[h]);
    }
#pragma unroll
    for (int off = 32; off; off >>= 1)
#pragma unroll
        for (int h = 0; h < 4; h++) ssum[h] += __shfl_xor(ssum[h], off);

    float inv[4];
#pragma unroll
    for (int h = 0; h < 4; h++) inv[h] = 1.f / (ssum[h] + 1e-16f);

    float acc[4] = {0.f, 0.f, 0.f, 0.f};
    for (int i = beg; i < end; i++) {
        int s = csr_src[i];  // uniform across wave
#pragma unroll
        for (int h = 0; h < 4; h++) {
            float w = __expf(lrelu(as0[(size_t)s * 4 + h] + ad[h]) - m[h]) * inv[h];
            acc[h] += w * h0[(size_t)s * 256 + h * 64 + lane];
        }
    }
#pragma unroll
    for (int h = 0; h < 4; h++) {
        float v = acc[h] + bias0[h * 64 + lane];
        h1[(size_t)wid * 256 + h * 64 + lane] = v > 0.f ? v : (__expf(v) - 1.f);  // ELU
    }
}

// ---------------- layer 1 GEMM: h2 = h1 @ W1  [N,256]x[256,64], fused alpha dots ----------------
// block = 256 threads, 64 rows/block; thread: row r=t>>2, col-group cg=t&3 (16 cols each)
__global__ __launch_bounds__(256) void gemm1_kernel(
        const float* __restrict__ h1, const float* __restrict__ W1,
        const float* __restrict__ a_src1, const float* __restrict__ a_dst1,
        int N, float* __restrict__ h2, float* __restrict__ as1, float* __restrict__ ad1) {
    __shared__ float xs[64][68];
    int block_row = blockIdx.x * 64;
    int t = threadIdx.x;
    int r = t >> 2, cg = t & 3;
    float acc[16];
#pragma unroll
    for (int j = 0; j < 16; j++) acc[j] = 0.f;

    for (int kc = 0; kc < 4; kc++) {
        __syncthreads();
        for (int i = t; i < 64 * 16; i += 256) {
            int rr = i >> 4, c4 = i & 15;
            int gr = block_row + rr;
            float4 v = (gr < N) ? ((const float4*)(h1 + (size_t)gr * 256 + kc * 64))[c4]
                                : make_float4(0, 0, 0, 0);
            *((float4*)&xs[rr][c4 * 4]) = v;
        }
        __syncthreads();
        for (int kk = 0; kk < 64; kk++) {
            float xv = xs[r][kk];
            const float4* w4 = (const float4*)(W1 + (size_t)(kc * 64 + kk) * 64 + cg * 16);
#pragma unroll
            for (int j4 = 0; j4 < 4; j4++) {
                float4 w = w4[j4];
                acc[j4 * 4 + 0] += xv * w.x;
                acc[j4 * 4 + 1] += xv * w.y;
                acc[j4 * 4 + 2] += xv * w.z;
                acc[j4 * 4 + 3] += xv * w.w;
            }
        }
    }
    int gr = block_row + r;
    float sdot = 0.f, ddot = 0.f;
#pragma unroll
    for (int j = 0; j < 16; j++) {
        sdot += acc[j] * a_src1[cg * 16 + j];
        ddot += acc[j] * a_dst1[cg * 16 + j];
    }
    // reduce over the 4 consecutive lanes sharing row r
    sdot += __shfl_xor(sdot, 1); sdot += __shfl_xor(sdot, 2);
    ddot += __shfl_xor(ddot, 1); ddot += __shfl_xor(ddot, 2);
    if (gr < N) {
        float4* o4 = (float4*)(h2 + (size_t)gr * 64 + cg * 16);
#pragma unroll
        for (int j4 = 0; j4 < 4; j4++)
            o4[j4] = make_float4(acc[j4 * 4], acc[j4 * 4 + 1], acc[j4 * 4 + 2], acc[j4 * 4 + 3]);
        if (cg == 0) { as1[gr] = sdot; ad1[gr] = ddot; }
    }
}

// ---------------- layer 1 aggregation: one wave per dst node (H=1, C=64) ----------------
__global__ __launch_bounds__(256) void agg1_kernel(
        const int* __restrict__ row_ptr, const int* __restrict__ csr_src,
        const float* __restrict__ h2, const float* __restrict__ as1, const float* __restrict__ ad1,
        const float* __restrict__ bias1, int N, float* __restrict__ out) {
    int wid = (blockIdx.x * blockDim.x + threadIdx.x) >> 6;
    int lane = threadIdx.x & 63;
    if (wid >= N) return;
    int beg = row_ptr[wid], end = row_ptr[wid + 1];
    float adv = ad1[wid];

    float m = -1e30f;
    for (int i = beg + lane; i < end; i += 64)
        m = fmaxf(m, lrelu(as1[csr_src[i]] + adv));
#pragma unroll
    for (int off = 32; off; off >>= 1) m = fmaxf(m, __shfl_xor(m, off));

    float ssum = 0.f;
    for (int i = beg + lane; i < end; i += 64)
        ssum += __expf(lrelu(as1[csr_src[i]] + adv) - m);
#pragma unroll
    for (int off = 32; off; off >>= 1) ssum += __shfl_xor(ssum, off);
    float inv = 1.f / (ssum + 1e-16f);

    float acc = 0.f;
    for (int i = beg; i < end; i++) {
        int s = csr_src[i];  // uniform across wave
        float w = __expf(lrelu(as1[s] + adv) - m) * inv;
        acc += w * h2[(size_t)s * 64 + lane];
    }
    out[(size_t)wid * 64 + lane] = acc + bias1[lane];
}

extern "C" void kernel_launch(void* const* d_in, const int* in_sizes, int n_in,
                              void* d_out, int out_size, void* d_ws, size_t ws_size,
                              hipStream_t stream) {
    const float* x    = (const float*)d_in[0];
    const int*   ei   = (const int*)d_in[1];
    const float* W0   = (const float*)d_in[2];
    const float* as0w = (const float*)d_in[3];
    const float* ad0w = (const float*)d_in[4];
    const float* b0   = (const float*)d_in[5];
    const float* W1   = (const float*)d_in[6];
    const float* as1w = (const float*)d_in[7];
    const float* ad1w = (const float*)d_in[8];
    const float* b1   = (const float*)d_in[9];
    float* out = (float*)d_out;

    const int HID = in_sizes[9];          // 64
    const int N   = out_size / HID;       // 50000
    const int E   = in_sizes[1] / 2;      // 800000
    const int* src = ei;
    const int* dst = ei + E;

    char* ws = (char*)d_ws;
    size_t off = 0;
    auto alloc = [&](size_t bytes) -> void* {
        off = (off + 255) & ~(size_t)255;
        void* p = ws + off;
        off += bytes;
        return p;
    };
    int*   counts  = (int*)alloc((size_t)N * 4);
    int*   cursor  = (int*)alloc((size_t)N * 4);
    int*   row_ptr = (int*)alloc((size_t)(N + 1) * 4);
    int*   csr     = (int*)alloc((size_t)(E + N) * 4);
    float* as0     = (float*)alloc((size_t)N * 4 * 4);
    float* ad0v    = (float*)alloc((size_t)N * 4 * 4);
    float* h0      = (float*)alloc((size_t)N * 256 * 4);
    float* h1      = (float*)alloc((size_t)N * 256 * 4);
    float* as1     = (float*)alloc((size_t)N * 4);
    float* ad1v    = (float*)alloc((size_t)N * 4);
    float* h2      = h0;  // h0 dead after agg0 -> reuse for h2 (N*64 <= N*256)

    hipMemsetAsync(counts, 0, (size_t)N * 4, stream);
    count_kernel<<<2048, 256, 0, stream>>>(dst, E, counts);
    scan_kernel<<<1, 1024, 0, stream>>>(counts, N, row_ptr, cursor);
    scatter_kernel<<<2048, 256, 0, stream>>>(src, dst, E, N, cursor, csr);

    gemm0_kernel<<<(N + 63) / 64, 256, 0, stream>>>(x, W0, as0w, ad0w, N, h0, as0, ad0v);
    agg0_kernel<<<(N * 64 + 255) / 256, 256, 0, stream>>>(row_ptr, csr, h0, as0, ad0v, b0, N, h1);
    gemm1_kernel<<<(N + 63) / 64, 256, 0, stream>>>(h1, W1, as1w, ad1w, N, h2, as1, ad1v);
    agg1_kernel<<<(N * 64 + 255) / 256, 256, 0, stream>>>(row_ptr, csr, h2, as1, ad1v, b1, N, out);
}

// Round 2
// 535.238 us; speedup vs baseline: 2.9244x; 2.9244x over previous
//
#include <hip/hip_runtime.h>

#define NEG_SLOPE 0.2f

__device__ __forceinline__ float lrelu(float x) { return x > 0.f ? x : NEG_SLOPE * x; }

// ---------------- CSR build ----------------
__global__ void count_kernel(const int* __restrict__ dst, int E, int* __restrict__ counts) {
    int stride = gridDim.x * blockDim.x;
    for (int i = blockIdx.x * blockDim.x + threadIdx.x; i < E; i += stride)
        atomicAdd(&counts[dst[i]], 1);
}

// chunked scan: thread t owns counts[t*chunk .. t*chunk+chunk), one 10-step block scan
__global__ __launch_bounds__(1024) void scan_kernel(const int* __restrict__ counts, int N,
                                                    int* __restrict__ row_ptr, int* __restrict__ cursor) {
    __shared__ int lds[1024];
    int t = threadIdx.x;
    int chunk = (N + 1023) >> 10;
    int beg = t * chunk;
    int end = min(beg + chunk, N);
    int sum = 0;
    for (int i = beg; i < end; i++) sum += counts[i] + 1;   // +1 = self loop
    lds[t] = sum;
    __syncthreads();
    for (int off = 1; off < 1024; off <<= 1) {
        int v = (t >= off) ? lds[t - off] : 0;
        __syncthreads();
        lds[t] += v;
        __syncthreads();
    }
    int run = lds[t] - sum;  // exclusive prefix
    for (int i = beg; i < end; i++) {
        row_ptr[i] = run;
        cursor[i] = run;
        run += counts[i] + 1;
    }
    if (t == 1023) row_ptr[N] = lds[1023];
}

__global__ void scatter_kernel(const int* __restrict__ src, const int* __restrict__ dst,
                               int E, int N, int* __restrict__ cursor, int* __restrict__ csr_src) {
    int stride = gridDim.x * blockDim.x;
    int total = E + N;
    for (int i = blockIdx.x * blockDim.x + threadIdx.x; i < total; i += stride) {
        int s, d;
        if (i < E) { s = src[i]; d = dst[i]; }
        else       { s = i - E;  d = s; }
        csr_src[atomicAdd(&cursor[d], 1)] = s;
    }
}

// ---------------- fused GEMM + alpha dots ----------------
// out[gr, head*64 + c] = sum_k X[gr,k] * W[k, head*64+c]
// alpha_s[gr*astride+head] = sum_c out[gr, head*64+c] * a_s[head*64+c]   (same for _d)
// block: 256 thr = 16(tr) x 16(tc); 64x64 tile; thread: 4 rows x 4 cols; K chunked by 64.
template<int K>
__global__ __launch_bounds__(256) void gemm_fused(
        const float* __restrict__ X, const float* __restrict__ W,
        const float* __restrict__ a_s, const float* __restrict__ a_d,
        int N, int ldw, float* __restrict__ out, int ldo,
        float* __restrict__ alpha_s, float* __restrict__ alpha_d, int astride) {
    __shared__ float xs[64][68];    // [row][k] pad->68: reads are 4-addr broadcast, 2-way alias only
    __shared__ float wsh[64][64];   // [k][col]
    const int head = blockIdx.y;
    const int block_row = blockIdx.x * 64;
    const int t = threadIdx.x;
    const int tr = t >> 4, tc = t & 15;

    float acc[4][4];
#pragma unroll
    for (int i = 0; i < 4; i++)
#pragma unroll
        for (int j = 0; j < 4; j++) acc[i][j] = 0.f;

    for (int kc = 0; kc < K; kc += 64) {
        __syncthreads();
#pragma unroll
        for (int ii = 0; ii < 4; ii++) {
            int i = t + ii * 256;
            int r = i >> 4, c4 = i & 15;
            int gr = block_row + r;
            float4 v = (gr < N) ? *(const float4*)(X + (size_t)gr * K + kc + c4 * 4)
                                : make_float4(0.f, 0.f, 0.f, 0.f);
            *(float4*)&xs[r][c4 * 4] = v;
            *(float4*)&wsh[r][c4 * 4] = *(const float4*)(W + (size_t)(kc + r) * ldw + head * 64 + c4 * 4);
        }
        __syncthreads();
#pragma unroll
        for (int k4 = 0; k4 < 16; k4++) {
            float4 xv[4], wv[4];
#pragma unroll
            for (int i = 0; i < 4; i++) xv[i] = *(const float4*)&xs[tr * 4 + i][k4 * 4];
#pragma unroll
            for (int e = 0; e < 4; e++) wv[e] = *(const float4*)&wsh[k4 * 4 + e][tc * 4];
#pragma unroll
            for (int i = 0; i < 4; i++) {
                float xe[4] = {xv[i].x, xv[i].y, xv[i].z, xv[i].w};
#pragma unroll
                for (int e = 0; e < 4; e++) {
                    acc[i][0] += xe[e] * wv[e].x;
                    acc[i][1] += xe[e] * wv[e].y;
                    acc[i][2] += xe[e] * wv[e].z;
                    acc[i][3] += xe[e] * wv[e].w;
                }
            }
        }
    }

    // alpha dots: partial over this thread's 4 cols, reduce across the 16 tc lanes
    float sdot[4], ddot[4];
#pragma unroll
    for (int i = 0; i < 4; i++) { sdot[i] = 0.f; ddot[i] = 0.f; }
#pragma unroll
    for (int i = 0; i < 4; i++)
#pragma unroll
        for (int j = 0; j < 4; j++) {
            float av = a_s[head * 64 + tc * 4 + j];
            float bv = a_d[head * 64 + tc * 4 + j];
            sdot[i] += acc[i][j] * av;
            ddot[i] += acc[i][j] * bv;
        }
#pragma unroll
    for (int off = 1; off < 16; off <<= 1)
#pragma unroll
        for (int i = 0; i < 4; i++) {
            sdot[i] += __shfl_xor(sdot[i], off);
            ddot[i] += __shfl_xor(ddot[i], off);
        }

#pragma unroll
    for (int i = 0; i < 4; i++) {
        int gr = block_row + tr * 4 + i;
        if (gr < N) {
            *(float4*)(out + (size_t)gr * ldo + head * 64 + tc * 4) =
                make_float4(acc[i][0], acc[i][1], acc[i][2], acc[i][3]);
            if (tc == 0) {
                alpha_s[(size_t)gr * astride + head] = sdot[i];
                alpha_d[(size_t)gr * astride + head] = ddot[i];
            }
        }
    }
}

// ---------------- layer 0 aggregation: one wave per dst node ----------------
__global__ __launch_bounds__(256) void agg0_kernel(
        const int* __restrict__ row_ptr, const int* __restrict__ csr_src,
        const float* __restrict__ h0, const float* __restrict__ as0, const float* __restrict__ ad0,
        const float* __restrict__ bias0, int N, float* __restrict__ h1) {
    int wid = (blockIdx.x * blockDim.x + threadIdx.x) >> 6;
    int lane = threadIdx.x & 63;
    if (wid >= N) return;
    int beg = row_ptr[wid], end = row_ptr[wid + 1];
    float ad[4];
#pragma unroll
    for (int h = 0; h < 4; h++) ad[h] = ad0[(size_t)wid * 4 + h];

    float m[4] = {-1e30f, -1e30f, -1e30f, -1e30f};
    for (int i = beg + lane; i < end; i += 64) {
        int s = csr_src[i];
#pragma unroll
        for (int h = 0; h < 4; h++) m[h] = fmaxf(m[h], lrelu(as0[(size_t)s * 4 + h] + ad[h]));
    }
#pragma unroll
    for (int off = 32; off; off >>= 1)
#pragma unroll
        for (int h = 0; h < 4; h++) m[h] = fmaxf(m[h], __shfl_xor(m[h], off));

    float ssum[4] = {0.f, 0.f, 0.f, 0.f};
    for (int i = beg + lane; i < end; i += 64) {
        int s = csr_src[i];
#pragma unroll
        for (int h = 0; h < 4; h++) ssum[h] += __expf(lrelu(as0[(size_t)s * 4 + h] + ad[h]) - m[h]);
    }
#pragma unroll
    for (int off = 32; off; off >>= 1)
#pragma unroll
        for (int h = 0; h < 4; h++) ssum[h] += __shfl_xor(ssum[h], off);

    float inv[4];
#pragma unroll
    for (int h = 0; h < 4; h++) inv[h] = 1.f / (ssum[h] + 1e-16f);

    float acc[4] = {0.f, 0.f, 0.f, 0.f};
    for (int i = beg; i < end; i++) {
        int s = csr_src[i];  // uniform across wave
#pragma unroll
        for (int h = 0; h < 4; h++) {
            float w = __expf(lrelu(as0[(size_t)s * 4 + h] + ad[h]) - m[h]) * inv[h];
            acc[h] += w * h0[(size_t)s * 256 + h * 64 + lane];
        }
    }
#pragma unroll
    for (int h = 0; h < 4; h++) {
        float v = acc[h] + bias0[h * 64 + lane];
        h1[(size_t)wid * 256 + h * 64 + lane] = v > 0.f ? v : (__expf(v) - 1.f);  // ELU
    }
}

// ---------------- layer 1 aggregation: one wave per dst node (H=1, C=64) ----------------
__global__ __launch_bounds__(256) void agg1_kernel(
        const int* __restrict__ row_ptr, const int* __restrict__ csr_src,
        const float* __restrict__ h2, const float* __restrict__ as1, const float* __restrict__ ad1,
        const float* __restrict__ bias1, int N, float* __restrict__ out) {
    int wid = (blockIdx.x * blockDim.x + threadIdx.x) >> 6;
    int lane = threadIdx.x & 63;
    if (wid >= N) return;
    int beg = row_ptr[wid], end = row_ptr[wid + 1];
    float adv = ad1[wid];

    float m = -1e30f;
    for (int i = beg + lane; i < end; i += 64)
        m = fmaxf(m, lrelu(as1[csr_src[i]] + adv));
#pragma unroll
    for (int off = 32; off; off >>= 1) m = fmaxf(m, __shfl_xor(m, off));

    float ssum = 0.f;
    for (int i = beg + lane; i < end; i += 64)
        ssum += __expf(lrelu(as1[csr_src[i]] + adv) - m);
#pragma unroll
    for (int off = 32; off; off >>= 1) ssum += __shfl_xor(ssum, off);
    float inv = 1.f / (ssum + 1e-16f);

    float acc = 0.f;
    for (int i = beg; i < end; i++) {
        int s = csr_src[i];  // uniform across wave
        float w = __expf(lrelu(as1[s] + adv) - m) * inv;
        acc += w * h2[(size_t)s * 64 + lane];
    }
    out[(size_t)wid * 64 + lane] = acc + bias1[lane];
}

extern "C" void kernel_launch(void* const* d_in, const int* in_sizes, int n_in,
                              void* d_out, int out_size, void* d_ws, size_t ws_size,
                              hipStream_t stream) {
    const float* x    = (const float*)d_in[0];
    const int*   ei   = (const int*)d_in[1];
    const float* W0   = (const float*)d_in[2];
    const float* as0w = (const float*)d_in[3];
    const float* ad0w = (const float*)d_in[4];
    const float* b0   = (const float*)d_in[5];
    const float* W1   = (const float*)d_in[6];
    const float* as1w = (const float*)d_in[7];
    const float* ad1w = (const float*)d_in[8];
    const float* b1   = (const float*)d_in[9];
    float* out = (float*)d_out;

    const int HID = in_sizes[9];          // 64
    const int N   = out_size / HID;       // 50000
    const int E   = in_sizes[1] / 2;      // 800000
    const int* src = ei;
    const int* dst = ei + E;

    char* ws = (char*)d_ws;
    size_t off = 0;
    auto alloc = [&](size_t bytes) -> void* {
        off = (off + 255) & ~(size_t)255;
        void* p = ws + off;
        off += bytes;
        return p;
    };
    int*   counts  = (int*)alloc((size_t)N * 4);
    int*   cursor  = (int*)alloc((size_t)N * 4);
    int*   row_ptr = (int*)alloc((size_t)(N + 1) * 4);
    int*   csr     = (int*)alloc((size_t)(E + N) * 4);
    float* as0     = (float*)alloc((size_t)N * 4 * 4);
    float* ad0v    = (float*)alloc((size_t)N * 4 * 4);
    float* h0      = (float*)alloc((size_t)N * 256 * 4);
    float* h1      = (float*)alloc((size_t)N * 256 * 4);
    float* as1     = (float*)alloc((size_t)N * 4);
    float* ad1v    = (float*)alloc((size_t)N * 4);
    float* h2      = h0;  // h0 dead after agg0 -> reuse for h2 (N*64 <= N*256)

    hipMemsetAsync(counts, 0, (size_t)N * 4, stream);
    count_kernel<<<2048, 256, 0, stream>>>(dst, E, counts);
    scan_kernel<<<1, 1024, 0, stream>>>(counts, N, row_ptr, cursor);
    scatter_kernel<<<2048, 256, 0, stream>>>(src, dst, E, N, cursor, csr);

    dim3 g0((N + 63) / 64, 4);
    gemm_fused<128><<<g0, 256, 0, stream>>>(x, W0, as0w, ad0w, N, 256, h0, 256, as0, ad0v, 4);
    agg0_kernel<<<(N * 64 + 255) / 256, 256, 0, stream>>>(row_ptr, csr, h0, as0, ad0v, b0, N, h1);
    dim3 g1((N + 63) / 64, 1);
    gemm_fused<256><<<g1, 256, 0, stream>>>(h1, W1, as1w, ad1w, N, 64, h2, 64, as1, ad1v, 1);
    agg1_kernel<<<(N * 64 + 255) / 256, 256, 0, stream>>>(row_ptr, csr, h2, as1, ad1v, b1, N, out);
}

// Round 3
// 489.680 us; speedup vs baseline: 3.1964x; 1.0930x over previous
//
#include <hip/hip_runtime.h>
#include <hip/hip_fp16.h>

#define NEG_SLOPE 0.2f

__device__ __forceinline__ float lrelu(float x) { return x > 0.f ? x : NEG_SLOPE * x; }

// ---------------- CSR build ----------------
__global__ void count_kernel(const int* __restrict__ dst, int E, int* __restrict__ counts) {
    int stride = gridDim.x * blockDim.x;
    for (int i = blockIdx.x * blockDim.x + threadIdx.x; i < E; i += stride)
        atomicAdd(&counts[dst[i]], 1);
}

// chunked scan: thread t owns counts[t*chunk .. t*chunk+chunk), one 10-step block scan
__global__ __launch_bounds__(1024) void scan_kernel(const int* __restrict__ counts, int N,
                                                    int* __restrict__ row_ptr, int* __restrict__ cursor) {
    __shared__ int lds[1024];
    int t = threadIdx.x;
    int chunk = (N + 1023) >> 10;
    int beg = t * chunk;
    int end = min(beg + chunk, N);
    int sum = 0;
    for (int i = beg; i < end; i++) sum += counts[i] + 1;   // +1 = self loop
    lds[t] = sum;
    __syncthreads();
    for (int off = 1; off < 1024; off <<= 1) {
        int v = (t >= off) ? lds[t - off] : 0;
        __syncthreads();
        lds[t] += v;
        __syncthreads();
    }
    int run = lds[t] - sum;  // exclusive prefix
    for (int i = beg; i < end; i++) {
        row_ptr[i] = run;
        cursor[i] = run;
        run += counts[i] + 1;
    }
    if (t == 1023) row_ptr[N] = lds[1023];
}

__global__ void scatter_kernel(const int* __restrict__ src, const int* __restrict__ dst,
                               int E, int N, int* __restrict__ cursor, int* __restrict__ csr_src) {
    int stride = gridDim.x * blockDim.x;
    int total = E + N;
    for (int i = blockIdx.x * blockDim.x + threadIdx.x; i < total; i += stride) {
        int s, d;
        if (i < E) { s = src[i]; d = dst[i]; }
        else       { s = i - E;  d = s; }
        csr_src[atomicAdd(&cursor[d], 1)] = s;
    }
}

// ---------------- fused GEMM + alpha dots, fp16 output ----------------
// out(half)[gr, head*64 + c] = sum_k X[gr,k] * W[k, head*64+c]
// alpha_s[gr*astride+head] = sum_c acc * a_s (fp32, from registers)
// block: 256 thr = 16(tr) x 16(tc); 64x64 tile; thread: 4 rows x 4 cols; K chunked by 64.
template<int K>
__global__ __launch_bounds__(256) void gemm_fused(
        const float* __restrict__ X, const float* __restrict__ W,
        const float* __restrict__ a_s, const float* __restrict__ a_d,
        int N, int ldw, __half* __restrict__ out, int ldo,
        float* __restrict__ alpha_s, float* __restrict__ alpha_d, int astride) {
    __shared__ float xs[64][68];
    __shared__ float wsh[64][64];
    const int head = blockIdx.y;
    const int block_row = blockIdx.x * 64;
    const int t = threadIdx.x;
    const int tr = t >> 4, tc = t & 15;

    float acc[4][4];
#pragma unroll
    for (int i = 0; i < 4; i++)
#pragma unroll
        for (int j = 0; j < 4; j++) acc[i][j] = 0.f;

    for (int kc = 0; kc < K; kc += 64) {
        __syncthreads();
#pragma unroll
        for (int ii = 0; ii < 4; ii++) {
            int i = t + ii * 256;
            int r = i >> 4, c4 = i & 15;
            int gr = block_row + r;
            float4 v = (gr < N) ? *(const float4*)(X + (size_t)gr * K + kc + c4 * 4)
                                : make_float4(0.f, 0.f, 0.f, 0.f);
            *(float4*)&xs[r][c4 * 4] = v;
            *(float4*)&wsh[r][c4 * 4] = *(const float4*)(W + (size_t)(kc + r) * ldw + head * 64 + c4 * 4);
        }
        __syncthreads();
#pragma unroll
        for (int k4 = 0; k4 < 16; k4++) {
            float4 xv[4], wv[4];
#pragma unroll
            for (int i = 0; i < 4; i++) xv[i] = *(const float4*)&xs[tr * 4 + i][k4 * 4];
#pragma unroll
            for (int e = 0; e < 4; e++) wv[e] = *(const float4*)&wsh[k4 * 4 + e][tc * 4];
#pragma unroll
            for (int i = 0; i < 4; i++) {
                float xe[4] = {xv[i].x, xv[i].y, xv[i].z, xv[i].w};
#pragma unroll
                for (int e = 0; e < 4; e++) {
                    acc[i][0] += xe[e] * wv[e].x;
                    acc[i][1] += xe[e] * wv[e].y;
                    acc[i][2] += xe[e] * wv[e].z;
                    acc[i][3] += xe[e] * wv[e].w;
                }
            }
        }
    }

    // alpha dots from fp32 registers
    float sdot[4], ddot[4];
#pragma unroll
    for (int i = 0; i < 4; i++) { sdot[i] = 0.f; ddot[i] = 0.f; }
#pragma unroll
    for (int i = 0; i < 4; i++)
#pragma unroll
        for (int j = 0; j < 4; j++) {
            float av = a_s[head * 64 + tc * 4 + j];
            float bv = a_d[head * 64 + tc * 4 + j];
            sdot[i] += acc[i][j] * av;
            ddot[i] += acc[i][j] * bv;
        }
#pragma unroll
    for (int off = 1; off < 16; off <<= 1)
#pragma unroll
        for (int i = 0; i < 4; i++) {
            sdot[i] += __shfl_xor(sdot[i], off);
            ddot[i] += __shfl_xor(ddot[i], off);
        }

#pragma unroll
    for (int i = 0; i < 4; i++) {
        int gr = block_row + tr * 4 + i;
        if (gr < N) {
            __half h4[4];
#pragma unroll
            for (int j = 0; j < 4; j++) h4[j] = __float2half_rn(acc[i][j]);
            *(uint2*)(out + (size_t)gr * ldo + head * 64 + tc * 4) = *(uint2*)h4;
            if (tc == 0) {
                alpha_s[(size_t)gr * astride + head] = sdot[i];
                alpha_d[(size_t)gr * astride + head] = ddot[i];
            }
        }
    }
}

// ---------------- layer 0 aggregation: one wave per dst node; lane owns 4 channels ----------------
// no max-subtraction: exponents are bounded (|e| <~ 10), softmax ratio is exact
__global__ __launch_bounds__(256) void agg0_kernel(
        const int* __restrict__ row_ptr, const int* __restrict__ csr_src,
        const __half* __restrict__ h0, const float* __restrict__ as0, const float* __restrict__ ad0,
        const float* __restrict__ bias0, int N, float* __restrict__ h1) {
    int wid = (blockIdx.x * blockDim.x + threadIdx.x) >> 6;
    int lane = threadIdx.x & 63;
    if (wid >= N) return;
    int beg = row_ptr[wid], end = row_ptr[wid + 1];
    float4 adv = *(const float4*)(ad0 + (size_t)wid * 4);
    float ad[4] = {adv.x, adv.y, adv.z, adv.w};

    float ssum[4] = {0.f, 0.f, 0.f, 0.f};
    for (int i = beg + lane; i < end; i += 64) {
        int s = csr_src[i];
        float4 asv = *(const float4*)(as0 + (size_t)s * 4);
        ssum[0] += __expf(lrelu(asv.x + ad[0]));
        ssum[1] += __expf(lrelu(asv.y + ad[1]));
        ssum[2] += __expf(lrelu(asv.z + ad[2]));
        ssum[3] += __expf(lrelu(asv.w + ad[3]));
    }
#pragma unroll
    for (int off = 32; off; off >>= 1)
#pragma unroll
        for (int h = 0; h < 4; h++) ssum[h] += __shfl_xor(ssum[h], off);

    const int myh = lane >> 4;           // head owning channels 4*lane..4*lane+3
    const float adh = ad[myh];
    const float myinv = 1.f / (ssum[myh] + 1e-16f);

    float acc[4] = {0.f, 0.f, 0.f, 0.f};
    for (int i = beg; i < end; i++) {
        int s = csr_src[i];  // uniform across wave
        float w = __expf(lrelu(as0[(size_t)s * 4 + myh] + adh)) * myinv;
        uint2 raw = *(const uint2*)(h0 + (size_t)s * 256 + lane * 4);
        __half2 p0 = *(__half2*)&raw.x;
        __half2 p1 = *(__half2*)&raw.y;
        float2 f0 = __half22float2(p0);
        float2 f1 = __half22float2(p1);
        acc[0] += w * f0.x;
        acc[1] += w * f0.y;
        acc[2] += w * f1.x;
        acc[3] += w * f1.y;
    }
    float4 o;
    float v;
    v = acc[0] + bias0[lane * 4 + 0]; o.x = v > 0.f ? v : (__expf(v) - 1.f);
    v = acc[1] + bias0[lane * 4 + 1]; o.y = v > 0.f ? v : (__expf(v) - 1.f);
    v = acc[2] + bias0[lane * 4 + 2]; o.z = v > 0.f ? v : (__expf(v) - 1.f);
    v = acc[3] + bias0[lane * 4 + 3]; o.w = v > 0.f ? v : (__expf(v) - 1.f);
    *(float4*)(h1 + (size_t)wid * 256 + lane * 4) = o;   // ELU applied
}

// ---------------- layer 1 aggregation: one wave per dst node (H=1, C=64) ----------------
__global__ __launch_bounds__(256) void agg1_kernel(
        const int* __restrict__ row_ptr, const int* __restrict__ csr_src,
        const __half* __restrict__ h2, const float* __restrict__ as1, const float* __restrict__ ad1,
        const float* __restrict__ bias1, int N, float* __restrict__ out) {
    int wid = (blockIdx.x * blockDim.x + threadIdx.x) >> 6;
    int lane = threadIdx.x & 63;
    if (wid >= N) return;
    int beg = row_ptr[wid], end = row_ptr[wid + 1];
    float adv = ad1[wid];

    float ssum = 0.f;
    for (int i = beg + lane; i < end; i += 64)
        ssum += __expf(lrelu(as1[csr_src[i]] + adv));
#pragma unroll
    for (int off = 32; off; off >>= 1) ssum += __shfl_xor(ssum, off);
    float inv = 1.f / (ssum + 1e-16f);

    float acc = 0.f;
    for (int i = beg; i < end; i++) {
        int s = csr_src[i];  // uniform across wave
        float w = __expf(lrelu(as1[s] + adv)) * inv;
        acc += w * __half2float(h2[(size_t)s * 64 + lane]);
    }
    out[(size_t)wid * 64 + lane] = acc + bias1[lane];
}

extern "C" void kernel_launch(void* const* d_in, const int* in_sizes, int n_in,
                              void* d_out, int out_size, void* d_ws, size_t ws_size,
                              hipStream_t stream) {
    const float* x    = (const float*)d_in[0];
    const int*   ei   = (const int*)d_in[1];
    const float* W0   = (const float*)d_in[2];
    const float* as0w = (const float*)d_in[3];
    const float* ad0w = (const float*)d_in[4];
    const float* b0   = (const float*)d_in[5];
    const float* W1   = (const float*)d_in[6];
    const float* as1w = (const float*)d_in[7];
    const float* ad1w = (const float*)d_in[8];
    const float* b1   = (const float*)d_in[9];
    float* out = (float*)d_out;

    const int HID = in_sizes[9];          // 64
    const int N   = out_size / HID;       // 50000
    const int E   = in_sizes[1] / 2;      // 800000
    const int* src = ei;
    const int* dst = ei + E;

    char* ws = (char*)d_ws;
    size_t off = 0;
    auto alloc = [&](size_t bytes) -> void* {
        off = (off + 255) & ~(size_t)255;
        void* p = ws + off;
        off += bytes;
        return p;
    };
    int*    counts  = (int*)alloc((size_t)N * 4);
    int*    cursor  = (int*)alloc((size_t)N * 4);
    int*    row_ptr = (int*)alloc((size_t)(N + 1) * 4);
    int*    csr     = (int*)alloc((size_t)(E + N) * 4);
    float*  as0     = (float*)alloc((size_t)N * 4 * 4);
    float*  ad0v    = (float*)alloc((size_t)N * 4 * 4);
    __half* h0      = (__half*)alloc((size_t)N * 256 * 2);
    float*  h1      = (float*)alloc((size_t)N * 256 * 4);
    float*  as1     = (float*)alloc((size_t)N * 4);
    float*  ad1v    = (float*)alloc((size_t)N * 4);
    __half* h2      = h0;  // h0 dead after agg0 -> reuse (N*64 halves <= N*256 halves)

    hipMemsetAsync(counts, 0, (size_t)N * 4, stream);
    count_kernel<<<2048, 256, 0, stream>>>(dst, E, counts);
    scan_kernel<<<1, 1024, 0, stream>>>(counts, N, row_ptr, cursor);
    scatter_kernel<<<2048, 256, 0, stream>>>(src, dst, E, N, cursor, csr);

    dim3 g0((N + 63) / 64, 4);
    gemm_fused<128><<<g0, 256, 0, stream>>>(x, W0, as0w, ad0w, N, 256, h0, 256, as0, ad0v, 4);
    agg0_kernel<<<(N * 64 + 255) / 256, 256, 0, stream>>>(row_ptr, csr, h0, as0, ad0v, b0, N, h1);
    dim3 g1((N + 63) / 64, 1);
    gemm_fused<256><<<g1, 256, 0, stream>>>(h1, W1, as1w, ad1w, N, 64, h2, 64, as1, ad1v, 1);
    agg1_kernel<<<(N * 64 + 255) / 256, 256, 0, stream>>>(row_ptr, csr, h2, as1, ad1v, b1, N, out);
}

// Round 4
// 476.011 us; speedup vs baseline: 3.2882x; 1.0287x over previous
//
#include <hip/hip_runtime.h>
#include <hip/hip_fp16.h>

#define NEG_SLOPE 0.2f

__device__ __forceinline__ float lrelu(float x) { return x > 0.f ? x : NEG_SLOPE * x; }
__device__ __forceinline__ float elu(float x) { return x > 0.f ? x : (__expf(x) - 1.f); }

// ---------------- CSR build ----------------
__global__ void count_kernel(const int* __restrict__ dst, int E, int* __restrict__ counts) {
    int stride = gridDim.x * blockDim.x;
    for (int i = blockIdx.x * blockDim.x + threadIdx.x; i < E; i += stride)
        atomicAdd(&counts[dst[i]], 1);
}

__global__ __launch_bounds__(1024) void scan_kernel(const int* __restrict__ counts, int N,
                                                    int* __restrict__ row_ptr, int* __restrict__ cursor) {
    __shared__ int lds[1024];
    int t = threadIdx.x;
    int chunk = (N + 1023) >> 10;
    int beg = t * chunk;
    int end = min(beg + chunk, N);
    int sum = 0;
    for (int i = beg; i < end; i++) sum += counts[i] + 1;   // +1 = self loop
    lds[t] = sum;
    __syncthreads();
    for (int off = 1; off < 1024; off <<= 1) {
        int v = (t >= off) ? lds[t - off] : 0;
        __syncthreads();
        lds[t] += v;
        __syncthreads();
    }
    int run = lds[t] - sum;  // exclusive prefix
    for (int i = beg; i < end; i++) {
        row_ptr[i] = run;
        cursor[i] = run;
        run += counts[i] + 1;
    }
    if (t == 1023) row_ptr[N] = lds[1023];
}

__global__ void scatter_kernel(const int* __restrict__ src, const int* __restrict__ dst,
                               int E, int N, int* __restrict__ cursor, int* __restrict__ csr_src) {
    int stride = gridDim.x * blockDim.x;
    int total = E + N;
    for (int i = blockIdx.x * blockDim.x + threadIdx.x; i < total; i += stride) {
        int s, d;
        if (i < E) { s = src[i]; d = dst[i]; }
        else       { s = i - E;  d = s; }
        csr_src[atomicAdd(&cursor[d], 1)] = s;
    }
}

// ---------------- Wa[k][0..3]=W0@a_src per head, [4..7]=W0@a_dst ----------------
__global__ __launch_bounds__(256) void prep_wa(const float* __restrict__ W0,
                                               const float* __restrict__ a_s, const float* __restrict__ a_d,
                                               float* __restrict__ Wa) {
    int t = blockIdx.x * 256 + threadIdx.x;  // 512 total: k=t>>2, h=t&3
    if (t >= 512) return;
    int k = t >> 2, h = t & 3;
    float ss = 0.f, dd = 0.f;
    for (int c = 0; c < 64; c++) {
        float w = W0[(size_t)k * 256 + h * 64 + c];
        ss += w * a_s[h * 64 + c];
        dd += w * a_d[h * 64 + c];
    }
    Wa[k * 8 + h] = ss;
    Wa[k * 8 + 4 + h] = dd;
}

// ---------------- gemv0: as0/ad0 = x @ Wa; also xh = fp16(x). one wave per node ----------------
__global__ __launch_bounds__(256) void gemv0_kernel(const float* __restrict__ x, const float* __restrict__ Wa,
                                                    int N, __half* __restrict__ xh,
                                                    float* __restrict__ as0, float* __restrict__ ad0) {
    int wid = (blockIdx.x * 256 + threadIdx.x) >> 6;
    int lane = threadIdx.x & 63;
    if (wid >= N) return;
    float2 xv = *(const float2*)(x + (size_t)wid * 128 + lane * 2);
    *(__half2*)(xh + (size_t)wid * 128 + lane * 2) = __floats2half2_rn(xv.x, xv.y);
    float p[8];
#pragma unroll
    for (int j = 0; j < 8; j++)
        p[j] = xv.x * Wa[(lane * 2) * 8 + j] + xv.y * Wa[(lane * 2 + 1) * 8 + j];
#pragma unroll
    for (int off = 32; off; off >>= 1)
#pragma unroll
        for (int j = 0; j < 8; j++) p[j] += __shfl_xor(p[j], off);
    if (lane == 0) {
        *(float4*)(as0 + (size_t)wid * 4) = make_float4(p[0], p[1], p[2], p[3]);
        *(float4*)(ad0 + (size_t)wid * 4) = make_float4(p[4], p[5], p[6], p[7]);
    }
}

// ---------------- layer 0 aggregation over x (fp16): aggx[N,4,128], one wave per node ----------------
// single pass: per 64-edge chunk, lane-parallel weight computation, shfl broadcast into serial gather
__global__ __launch_bounds__(256) void agg0_kernel(
        const int* __restrict__ row_ptr, const int* __restrict__ csr,
        const __half* __restrict__ xh, const float* __restrict__ as0, const float* __restrict__ ad0,
        int N, __half* __restrict__ aggx) {
    int wid = (blockIdx.x * 256 + threadIdx.x) >> 6;
    int lane = threadIdx.x & 63;
    if (wid >= N) return;
    int beg = row_ptr[wid], end = row_ptr[wid + 1];
    float4 adv = *(const float4*)(ad0 + (size_t)wid * 4);

    float wsum[4] = {0.f, 0.f, 0.f, 0.f};
    float acc[4][2] = {};
    for (int chunk = beg; chunk < end; chunk += 64) {
        int nv = min(64, end - chunk);
        int s_l = 0;
        float4 w4 = make_float4(0.f, 0.f, 0.f, 0.f);
        if (lane < nv) {
            s_l = csr[chunk + lane];
            float4 asv = *(const float4*)(as0 + (size_t)s_l * 4);
            w4.x = __expf(lrelu(asv.x + adv.x));
            w4.y = __expf(lrelu(asv.y + adv.y));
            w4.z = __expf(lrelu(asv.z + adv.z));
            w4.w = __expf(lrelu(asv.w + adv.w));
        }
        wsum[0] += w4.x; wsum[1] += w4.y; wsum[2] += w4.z; wsum[3] += w4.w;
        for (int j = 0; j < nv; j++) {
            int s = __shfl(s_l, j);
            float wx = __shfl(w4.x, j);
            float wy = __shfl(w4.y, j);
            float wz = __shfl(w4.z, j);
            float ww = __shfl(w4.w, j);
            float2 f = __half22float2(*(const __half2*)(xh + (size_t)s * 128 + lane * 2));
            acc[0][0] += wx * f.x; acc[0][1] += wx * f.y;
            acc[1][0] += wy * f.x; acc[1][1] += wy * f.y;
            acc[2][0] += wz * f.x; acc[2][1] += wz * f.y;
            acc[3][0] += ww * f.x; acc[3][1] += ww * f.y;
        }
    }
#pragma unroll
    for (int off = 32; off; off >>= 1)
#pragma unroll
        for (int h = 0; h < 4; h++) wsum[h] += __shfl_xor(wsum[h], off);
#pragma unroll
    for (int h = 0; h < 4; h++) {
        float inv = 1.f / (wsum[h] + 1e-16f);
        *(__half2*)(aggx + ((size_t)wid * 4 + h) * 128 + lane * 2) =
            __floats2half2_rn(acc[h][0] * inv, acc[h][1] * inv);
    }
}

// ---------------- gemmA: h1 = ELU(aggx_head @ W0_head + b0), fp16 in/out ----------------
__global__ __launch_bounds__(256) void gemmA_kernel(
        const __half* __restrict__ aggx, const float* __restrict__ W0, const float* __restrict__ bias0,
        int N, __half* __restrict__ h1) {
    __shared__ float xs[64][68];
    __shared__ float wsh[64][64];
    const int head = blockIdx.y;
    const int block_row = blockIdx.x * 64;
    const int t = threadIdx.x;
    const int tr = t >> 4, tc = t & 15;
    float acc[4][4] = {};
    for (int kc = 0; kc < 128; kc += 64) {
        __syncthreads();
#pragma unroll
        for (int ii = 0; ii < 4; ii++) {
            int i = t + ii * 256;
            int r = i >> 4, c4 = i & 15;
            int gr = block_row + r;
            float4 xv = make_float4(0.f, 0.f, 0.f, 0.f);
            if (gr < N) {
                uint2 u = *(const uint2*)(aggx + ((size_t)gr * 4 + head) * 128 + kc + c4 * 4);
                float2 f0 = __half22float2(*(__half2*)&u.x);
                float2 f1 = __half22float2(*(__half2*)&u.y);
                xv = make_float4(f0.x, f0.y, f1.x, f1.y);
            }
            *(float4*)&xs[r][c4 * 4] = xv;
            *(float4*)&wsh[r][c4 * 4] = *(const float4*)(W0 + (size_t)(kc + r) * 256 + head * 64 + c4 * 4);
        }
        __syncthreads();
#pragma unroll
        for (int k4 = 0; k4 < 16; k4++) {
            float4 xv[4], wv[4];
#pragma unroll
            for (int i = 0; i < 4; i++) xv[i] = *(const float4*)&xs[tr * 4 + i][k4 * 4];
#pragma unroll
            for (int e = 0; e < 4; e++) wv[e] = *(const float4*)&wsh[k4 * 4 + e][tc * 4];
#pragma unroll
            for (int i = 0; i < 4; i++) {
                float xe[4] = {xv[i].x, xv[i].y, xv[i].z, xv[i].w};
#pragma unroll
                for (int e = 0; e < 4; e++) {
                    acc[i][0] += xe[e] * wv[e].x;
                    acc[i][1] += xe[e] * wv[e].y;
                    acc[i][2] += xe[e] * wv[e].z;
                    acc[i][3] += xe[e] * wv[e].w;
                }
            }
        }
    }
#pragma unroll
    for (int i = 0; i < 4; i++) {
        int gr = block_row + tr * 4 + i;
        if (gr < N) {
            __half h4[4];
#pragma unroll
            for (int j = 0; j < 4; j++) {
                float v = acc[i][j] + bias0[head * 64 + tc * 4 + j];
                h4[j] = __float2half_rn(elu(v));
            }
            *(uint2*)(h1 + (size_t)gr * 256 + head * 64 + tc * 4) = *(uint2*)h4;
        }
    }
}

// ---------------- gemmB: h2 = h1 @ W1 (fp16 in/out) + fused alpha1 dots ----------------
__global__ __launch_bounds__(256) void gemmB_kernel(
        const __half* __restrict__ h1, const float* __restrict__ W1,
        const float* __restrict__ a_s, const float* __restrict__ a_d,
        int N, __half* __restrict__ h2, float* __restrict__ as1, float* __restrict__ ad1) {
    __shared__ float xs[64][68];
    __shared__ float wsh[64][64];
    const int block_row = blockIdx.x * 64;
    const int t = threadIdx.x;
    const int tr = t >> 4, tc = t & 15;
    float acc[4][4] = {};
    for (int kc = 0; kc < 256; kc += 64) {
        __syncthreads();
#pragma unroll
        for (int ii = 0; ii < 4; ii++) {
            int i = t + ii * 256;
            int r = i >> 4, c4 = i & 15;
            int gr = block_row + r;
            float4 xv = make_float4(0.f, 0.f, 0.f, 0.f);
            if (gr < N) {
                uint2 u = *(const uint2*)(h1 + (size_t)gr * 256 + kc + c4 * 4);
                float2 f0 = __half22float2(*(__half2*)&u.x);
                float2 f1 = __half22float2(*(__half2*)&u.y);
                xv = make_float4(f0.x, f0.y, f1.x, f1.y);
            }
            *(float4*)&xs[r][c4 * 4] = xv;
            *(float4*)&wsh[r][c4 * 4] = *(const float4*)(W1 + (size_t)(kc + r) * 64 + c4 * 4);
        }
        __syncthreads();
#pragma unroll
        for (int k4 = 0; k4 < 16; k4++) {
            float4 xv[4], wv[4];
#pragma unroll
            for (int i = 0; i < 4; i++) xv[i] = *(const float4*)&xs[tr * 4 + i][k4 * 4];
#pragma unroll
            for (int e = 0; e < 4; e++) wv[e] = *(const float4*)&wsh[k4 * 4 + e][tc * 4];
#pragma unroll
            for (int i = 0; i < 4; i++) {
                float xe[4] = {xv[i].x, xv[i].y, xv[i].z, xv[i].w};
#pragma unroll
                for (int e = 0; e < 4; e++) {
                    acc[i][0] += xe[e] * wv[e].x;
                    acc[i][1] += xe[e] * wv[e].y;
                    acc[i][2] += xe[e] * wv[e].z;
                    acc[i][3] += xe[e] * wv[e].w;
                }
            }
        }
    }
    float sdot[4], ddot[4];
#pragma unroll
    for (int i = 0; i < 4; i++) { sdot[i] = 0.f; ddot[i] = 0.f; }
#pragma unroll
    for (int i = 0; i < 4; i++)
#pragma unroll
        for (int j = 0; j < 4; j++) {
            sdot[i] += acc[i][j] * a_s[tc * 4 + j];
            ddot[i] += acc[i][j] * a_d[tc * 4 + j];
        }
#pragma unroll
    for (int off = 1; off < 16; off <<= 1)
#pragma unroll
        for (int i = 0; i < 4; i++) {
            sdot[i] += __shfl_xor(sdot[i], off);
            ddot[i] += __shfl_xor(ddot[i], off);
        }
#pragma unroll
    for (int i = 0; i < 4; i++) {
        int gr = block_row + tr * 4 + i;
        if (gr < N) {
            __half h4[4];
#pragma unroll
            for (int j = 0; j < 4; j++) h4[j] = __float2half_rn(acc[i][j]);
            *(uint2*)(h2 + (size_t)gr * 64 + tc * 4) = *(uint2*)h4;
            if (tc == 0) { as1[gr] = sdot[i]; ad1[gr] = ddot[i]; }
        }
    }
}

// ---------------- layer 1 aggregation (H=1, C=64): one wave per node, single pass ----------------
__global__ __launch_bounds__(256) void agg1_kernel(
        const int* __restrict__ row_ptr, const int* __restrict__ csr,
        const __half* __restrict__ h2, const float* __restrict__ as1, const float* __restrict__ ad1,
        const float* __restrict__ bias1, int N, float* __restrict__ out) {
    int wid = (blockIdx.x * 256 + threadIdx.x) >> 6;
    int lane = threadIdx.x & 63;
    if (wid >= N) return;
    int beg = row_ptr[wid], end = row_ptr[wid + 1];
    float adv = ad1[wid];

    float wsum = 0.f, acc = 0.f;
    for (int chunk = beg; chunk < end; chunk += 64) {
        int nv = min(64, end - chunk);
        int s_l = 0;
        float w_l = 0.f;
        if (lane < nv) {
            s_l = csr[chunk + lane];
            w_l = __expf(lrelu(as1[s_l] + adv));
        }
        wsum += w_l;
        for (int j = 0; j < nv; j++) {
            int s = __shfl(s_l, j);
            float w = __shfl(w_l, j);
            acc += w * __half2float(h2[(size_t)s * 64 + lane]);
        }
    }
#pragma unroll
    for (int off = 32; off; off >>= 1) wsum += __shfl_xor(wsum, off);
    out[(size_t)wid * 64 + lane] = acc / (wsum + 1e-16f) + bias1[lane];
}

extern "C" void kernel_launch(void* const* d_in, const int* in_sizes, int n_in,
                              void* d_out, int out_size, void* d_ws, size_t ws_size,
                              hipStream_t stream) {
    const float* x    = (const float*)d_in[0];
    const int*   ei   = (const int*)d_in[1];
    const float* W0   = (const float*)d_in[2];
    const float* as0w = (const float*)d_in[3];
    const float* ad0w = (const float*)d_in[4];
    const float* b0   = (const float*)d_in[5];
    const float* W1   = (const float*)d_in[6];
    const float* as1w = (const float*)d_in[7];
    const float* ad1w = (const float*)d_in[8];
    const float* b1   = (const float*)d_in[9];
    float* out = (float*)d_out;

    const int HID = in_sizes[9];          // 64
    const int N   = out_size / HID;       // 50000
    const int E   = in_sizes[1] / 2;      // 800000
    const int* src = ei;
    const int* dst = ei + E;

    char* ws = (char*)d_ws;
    size_t off = 0;
    auto alloc = [&](size_t bytes) -> void* {
        off = (off + 255) & ~(size_t)255;
        void* p = ws + off;
        off += bytes;
        return p;
    };
    int*    counts  = (int*)alloc((size_t)N * 4);
    int*    cursor  = (int*)alloc((size_t)N * 4);
    int*    row_ptr = (int*)alloc((size_t)(N + 1) * 4);
    int*    csr     = (int*)alloc((size_t)(E + N) * 4);
    float*  Wa      = (float*)alloc(128 * 8 * 4);
    float*  as0     = (float*)alloc((size_t)N * 4 * 4);
    float*  ad0v    = (float*)alloc((size_t)N * 4 * 4);
    __half* xh      = (__half*)alloc((size_t)N * 128 * 2);
    __half* aggx    = (__half*)alloc((size_t)N * 512 * 2);
    __half* h1      = (__half*)alloc((size_t)N * 256 * 2);
    // aliases: dead buffers reused
    __half* h2      = xh;              // xh dead after agg0; N*64 <= N*128 halves
    float*  as1     = as0;             // as0 dead after agg0
    float*  ad1v    = ad0v;

    hipMemsetAsync(counts, 0, (size_t)N * 4, stream);
    count_kernel<<<2048, 256, 0, stream>>>(dst, E, counts);
    scan_kernel<<<1, 1024, 0, stream>>>(counts, N, row_ptr, cursor);
    scatter_kernel<<<2048, 256, 0, stream>>>(src, dst, E, N, cursor, csr);

    prep_wa<<<2, 256, 0, stream>>>(W0, as0w, ad0w, Wa);
    gemv0_kernel<<<(N * 64 + 255) / 256, 256, 0, stream>>>(x, Wa, N, xh, as0, ad0v);
    agg0_kernel<<<(N * 64 + 255) / 256, 256, 0, stream>>>(row_ptr, csr, xh, as0, ad0v, N, aggx);
    dim3 gA((N + 63) / 64, 4);
    gemmA_kernel<<<gA, 256, 0, stream>>>(aggx, W0, b0, N, h1);
    gemmB_kernel<<<(N + 63) / 64, 256, 0, stream>>>(h1, W1, as1w, ad1w, N, h2, as1, ad1v);
    agg1_kernel<<<(N * 64 + 255) / 256, 256, 0, stream>>>(row_ptr, csr, h2, as1, ad1v, b1, N, out);
}

// Round 5
// 376.317 us; speedup vs baseline: 4.1594x; 1.2649x over previous
//
#include <hip/hip_runtime.h>
#include <hip/hip_fp16.h>

#define NEG_SLOPE 0.2f

__device__ __forceinline__ float lrelu(float x) { return x > 0.f ? x : NEG_SLOPE * x; }
__device__ __forceinline__ float elu(float x) { return x > 0.f ? x : (__expf(x) - 1.f); }

// ---------------- CSR build ----------------
__global__ void count_kernel(const int* __restrict__ dst, int E, int* __restrict__ counts) {
    int stride = gridDim.x * blockDim.x;
    for (int i = blockIdx.x * blockDim.x + threadIdx.x; i < E; i += stride)
        atomicAdd(&counts[dst[i]], 1);
}

// hierarchical scan of (counts[i]+1), 1024 elements per block
__global__ __launch_bounds__(256) void scan1_kernel(const int* __restrict__ counts, int N,
                                                    int* __restrict__ local, int* __restrict__ partials) {
    __shared__ int lds[256];
    int t = threadIdx.x;
    int base = blockIdx.x * 1024 + t * 4;
    int e[4];
#pragma unroll
    for (int j = 0; j < 4; j++) e[j] = (base + j < N) ? counts[base + j] + 1 : 0;  // +1 = self loop
    int s = e[0] + e[1] + e[2] + e[3];
    lds[t] = s;
    __syncthreads();
    for (int off = 1; off < 256; off <<= 1) {
        int v = (t >= off) ? lds[t - off] : 0;
        __syncthreads();
        lds[t] += v;
        __syncthreads();
    }
    int run = lds[t] - s;   // exclusive prefix within block
    if (t == 255) partials[blockIdx.x] = lds[255];
#pragma unroll
    for (int j = 0; j < 4; j++) {
        if (base + j < N) local[base + j] = run;
        run += e[j];
    }
}

__global__ __launch_bounds__(256) void scan2_kernel(int* __restrict__ partials, int nb,
                                                    int* __restrict__ total) {
    __shared__ int lds[256];
    int t = threadIdx.x;
    int v = (t < nb) ? partials[t] : 0;
    lds[t] = v;
    __syncthreads();
    for (int off = 1; off < 256; off <<= 1) {
        int u = (t >= off) ? lds[t - off] : 0;
        __syncthreads();
        lds[t] += u;
        __syncthreads();
    }
    if (t < nb) partials[t] = lds[t] - v;  // exclusive
    if (t == 255) *total = lds[255];
}

__global__ __launch_bounds__(256) void scan3_kernel(const int* __restrict__ partials, int N,
                                                    int* __restrict__ row_ptr, int* __restrict__ cursor) {
    int base = blockIdx.x * 1024 + threadIdx.x * 4;
    int off = partials[blockIdx.x];
    if (base + 3 < N) {
        int4 v = *(const int4*)(cursor + base);
        v.x += off; v.y += off; v.z += off; v.w += off;
        *(int4*)(row_ptr + base) = v;
        *(int4*)(cursor + base) = v;
    } else {
#pragma unroll
        for (int j = 0; j < 4; j++) {
            int i = base + j;
            if (i < N) { int v = cursor[i] + off; row_ptr[i] = v; cursor[i] = v; }
        }
    }
}

__global__ void scatter_kernel(const int* __restrict__ src, const int* __restrict__ dst,
                               int E, int N, int* __restrict__ cursor, int* __restrict__ csr_src) {
    int stride = gridDim.x * blockDim.x;
    int total = E + N;
    for (int i = blockIdx.x * blockDim.x + threadIdx.x; i < total; i += stride) {
        int s, d;
        if (i < E) { s = src[i]; d = dst[i]; }
        else       { s = i - E;  d = s; }
        csr_src[atomicAdd(&cursor[d], 1)] = s;
    }
}

// ---------------- Wa[k][0..3]=W0@a_src per head, [4..7]=W0@a_dst ----------------
__global__ __launch_bounds__(256) void prep_wa(const float* __restrict__ W0,
                                               const float* __restrict__ a_s, const float* __restrict__ a_d,
                                               float* __restrict__ Wa) {
    int t = blockIdx.x * 256 + threadIdx.x;  // 512 total: k=t>>2, h=t&3
    if (t >= 512) return;
    int k = t >> 2, h = t & 3;
    float ss = 0.f, dd = 0.f;
    for (int c = 0; c < 64; c++) {
        float w = W0[(size_t)k * 256 + h * 64 + c];
        ss += w * a_s[h * 64 + c];
        dd += w * a_d[h * 64 + c];
    }
    Wa[k * 8 + h] = ss;
    Wa[k * 8 + 4 + h] = dd;
}

// ---------------- gemv0: as0/ad0 = x @ Wa; also xh = fp16(x). one wave per node ----------------
__global__ __launch_bounds__(256) void gemv0_kernel(const float* __restrict__ x, const float* __restrict__ Wa,
                                                    int N, __half* __restrict__ xh,
                                                    float* __restrict__ as0, float* __restrict__ ad0) {
    int wid = (blockIdx.x * 256 + threadIdx.x) >> 6;
    int lane = threadIdx.x & 63;
    if (wid >= N) return;
    float2 xv = *(const float2*)(x + (size_t)wid * 128 + lane * 2);
    *(__half2*)(xh + (size_t)wid * 128 + lane * 2) = __floats2half2_rn(xv.x, xv.y);
    float p[8];
#pragma unroll
    for (int j = 0; j < 8; j++)
        p[j] = xv.x * Wa[(lane * 2) * 8 + j] + xv.y * Wa[(lane * 2 + 1) * 8 + j];
#pragma unroll
    for (int off = 32; off; off >>= 1)
#pragma unroll
        for (int j = 0; j < 8; j++) p[j] += __shfl_xor(p[j], off);
    if (lane == 0) {
        *(float4*)(as0 + (size_t)wid * 4) = make_float4(p[0], p[1], p[2], p[3]);
        *(float4*)(ad0 + (size_t)wid * 4) = make_float4(p[4], p[5], p[6], p[7]);
    }
}

// ---------------- layer 0 aggregation over x (fp16): aggx[N,4,128], one wave per node ----------------
__global__ __launch_bounds__(256) void agg0_kernel(
        const int* __restrict__ row_ptr, const int* __restrict__ csr,
        const __half* __restrict__ xh, const float* __restrict__ as0, const float* __restrict__ ad0,
        int N, __half* __restrict__ aggx) {
    int wid = (blockIdx.x * 256 + threadIdx.x) >> 6;
    int lane = threadIdx.x & 63;
    if (wid >= N) return;
    int beg = row_ptr[wid], end = row_ptr[wid + 1];
    float4 adv = *(const float4*)(ad0 + (size_t)wid * 4);

    float wsum[4] = {0.f, 0.f, 0.f, 0.f};
    float acc[4][2] = {};
    for (int chunk = beg; chunk < end; chunk += 64) {
        int nv = min(64, end - chunk);
        int s_l = 0;
        float4 w4 = make_float4(0.f, 0.f, 0.f, 0.f);
        if (lane < nv) {
            s_l = csr[chunk + lane];
            float4 asv = *(const float4*)(as0 + (size_t)s_l * 4);
            w4.x = __expf(lrelu(asv.x + adv.x));
            w4.y = __expf(lrelu(asv.y + adv.y));
            w4.z = __expf(lrelu(asv.z + adv.z));
            w4.w = __expf(lrelu(asv.w + adv.w));
        }
        wsum[0] += w4.x; wsum[1] += w4.y; wsum[2] += w4.z; wsum[3] += w4.w;
        for (int j = 0; j < nv; j++) {
            int s = __shfl(s_l, j);
            float wx = __shfl(w4.x, j);
            float wy = __shfl(w4.y, j);
            float wz = __shfl(w4.z, j);
            float ww = __shfl(w4.w, j);
            float2 f = __half22float2(*(const __half2*)(xh + (size_t)s * 128 + lane * 2));
            acc[0][0] += wx * f.x; acc[0][1] += wx * f.y;
            acc[1][0] += wy * f.x; acc[1][1] += wy * f.y;
            acc[2][0] += wz * f.x; acc[2][1] += wz * f.y;
            acc[3][0] += ww * f.x; acc[3][1] += ww * f.y;
        }
    }
#pragma unroll
    for (int off = 32; off; off >>= 1)
#pragma unroll
        for (int h = 0; h < 4; h++) wsum[h] += __shfl_xor(wsum[h], off);
#pragma unroll
    for (int h = 0; h < 4; h++) {
        float inv = 1.f / (wsum[h] + 1e-16f);
        *(__half2*)(aggx + ((size_t)wid * 4 + h) * 128 + lane * 2) =
            __floats2half2_rn(acc[h][0] * inv, acc[h][1] * inv);
    }
}

// ---------------- gemmA: h1 = ELU(aggx_head @ W0_head + b0), fp16 in/out ----------------
__global__ __launch_bounds__(256) void gemmA_kernel(
        const __half* __restrict__ aggx, const float* __restrict__ W0, const float* __restrict__ bias0,
        int N, __half* __restrict__ h1) {
    __shared__ float xs[64][68];
    __shared__ float wsh[64][64];
    const int head = blockIdx.y;
    const int block_row = blockIdx.x * 64;
    const int t = threadIdx.x;
    const int tr = t >> 4, tc = t & 15;
    float acc[4][4] = {};
    for (int kc = 0; kc < 128; kc += 64) {
        __syncthreads();
#pragma unroll
        for (int ii = 0; ii < 4; ii++) {
            int i = t + ii * 256;
            int r = i >> 4, c4 = i & 15;
            int gr = block_row + r;
            float4 xv = make_float4(0.f, 0.f, 0.f, 0.f);
            if (gr < N) {
                uint2 u = *(const uint2*)(aggx + ((size_t)gr * 4 + head) * 128 + kc + c4 * 4);
                float2 f0 = __half22float2(*(__half2*)&u.x);
                float2 f1 = __half22float2(*(__half2*)&u.y);
                xv = make_float4(f0.x, f0.y, f1.x, f1.y);
            }
            *(float4*)&xs[r][c4 * 4] = xv;
            *(float4*)&wsh[r][c4 * 4] = *(const float4*)(W0 + (size_t)(kc + r) * 256 + head * 64 + c4 * 4);
        }
        __syncthreads();
#pragma unroll
        for (int k4 = 0; k4 < 16; k4++) {
            float4 xv[4], wv[4];
#pragma unroll
            for (int i = 0; i < 4; i++) xv[i] = *(const float4*)&xs[tr * 4 + i][k4 * 4];
#pragma unroll
            for (int e = 0; e < 4; e++) wv[e] = *(const float4*)&wsh[k4 * 4 + e][tc * 4];
#pragma unroll
            for (int i = 0; i < 4; i++) {
                float xe[4] = {xv[i].x, xv[i].y, xv[i].z, xv[i].w};
#pragma unroll
                for (int e = 0; e < 4; e++) {
                    acc[i][0] += xe[e] * wv[e].x;
                    acc[i][1] += xe[e] * wv[e].y;
                    acc[i][2] += xe[e] * wv[e].z;
                    acc[i][3] += xe[e] * wv[e].w;
                }
            }
        }
    }
#pragma unroll
    for (int i = 0; i < 4; i++) {
        int gr = block_row + tr * 4 + i;
        if (gr < N) {
            __half h4[4];
#pragma unroll
            for (int j = 0; j < 4; j++) {
                float v = acc[i][j] + bias0[head * 64 + tc * 4 + j];
                h4[j] = __float2half_rn(elu(v));
            }
            *(uint2*)(h1 + (size_t)gr * 256 + head * 64 + tc * 4) = *(uint2*)h4;
        }
    }
}

// ---------------- gemmB: h2 = h1 @ W1 (fp16 in/out) + fused alpha1 dots ----------------
__global__ __launch_bounds__(256) void gemmB_kernel(
        const __half* __restrict__ h1, const float* __restrict__ W1,
        const float* __restrict__ a_s, const float* __restrict__ a_d,
        int N, __half* __restrict__ h2, float* __restrict__ as1, float* __restrict__ ad1) {
    __shared__ float xs[64][68];
    __shared__ float wsh[64][64];
    const int block_row = blockIdx.x * 64;
    const int t = threadIdx.x;
    const int tr = t >> 4, tc = t & 15;
    float acc[4][4] = {};
    for (int kc = 0; kc < 256; kc += 64) {
        __syncthreads();
#pragma unroll
        for (int ii = 0; ii < 4; ii++) {
            int i = t + ii * 256;
            int r = i >> 4, c4 = i & 15;
            int gr = block_row + r;
            float4 xv = make_float4(0.f, 0.f, 0.f, 0.f);
            if (gr < N) {
                uint2 u = *(const uint2*)(h1 + (size_t)gr * 256 + kc + c4 * 4);
                float2 f0 = __half22float2(*(__half2*)&u.x);
                float2 f1 = __half22float2(*(__half2*)&u.y);
                xv = make_float4(f0.x, f0.y, f1.x, f1.y);
            }
            *(float4*)&xs[r][c4 * 4] = xv;
            *(float4*)&wsh[r][c4 * 4] = *(const float4*)(W1 + (size_t)(kc + r) * 64 + c4 * 4);
        }
        __syncthreads();
#pragma unroll
        for (int k4 = 0; k4 < 16; k4++) {
            float4 xv[4], wv[4];
#pragma unroll
            for (int i = 0; i < 4; i++) xv[i] = *(const float4*)&xs[tr * 4 + i][k4 * 4];
#pragma unroll
            for (int e = 0; e < 4; e++) wv[e] = *(const float4*)&wsh[k4 * 4 + e][tc * 4];
#pragma unroll
            for (int i = 0; i < 4; i++) {
                float xe[4] = {xv[i].x, xv[i].y, xv[i].z, xv[i].w};
#pragma unroll
                for (int e = 0; e < 4; e++) {
                    acc[i][0] += xe[e] * wv[e].x;
                    acc[i][1] += xe[e] * wv[e].y;
                    acc[i][2] += xe[e] * wv[e].z;
                    acc[i][3] += xe[e] * wv[e].w;
                }
            }
        }
    }
    float sdot[4], ddot[4];
#pragma unroll
    for (int i = 0; i < 4; i++) { sdot[i] = 0.f; ddot[i] = 0.f; }
#pragma unroll
    for (int i = 0; i < 4; i++)
#pragma unroll
        for (int j = 0; j < 4; j++) {
            sdot[i] += acc[i][j] * a_s[tc * 4 + j];
            ddot[i] += acc[i][j] * a_d[tc * 4 + j];
        }
#pragma unroll
    for (int off = 1; off < 16; off <<= 1)
#pragma unroll
        for (int i = 0; i < 4; i++) {
            sdot[i] += __shfl_xor(sdot[i], off);
            ddot[i] += __shfl_xor(ddot[i], off);
        }
#pragma unroll
    for (int i = 0; i < 4; i++) {
        int gr = block_row + tr * 4 + i;
        if (gr < N) {
            __half h4[4];
#pragma unroll
            for (int j = 0; j < 4; j++) h4[j] = __float2half_rn(acc[i][j]);
            *(uint2*)(h2 + (size_t)gr * 64 + tc * 4) = *(uint2*)h4;
            if (tc == 0) { as1[gr] = sdot[i]; ad1[gr] = ddot[i]; }
        }
    }
}

// ---------------- layer 1 aggregation (H=1, C=64): one wave per node, single pass ----------------
__global__ __launch_bounds__(256) void agg1_kernel(
        const int* __restrict__ row_ptr, const int* __restrict__ csr,
        const __half* __restrict__ h2, const float* __restrict__ as1, const float* __restrict__ ad1,
        const float* __restrict__ bias1, int N, float* __restrict__ out) {
    int wid = (blockIdx.x * 256 + threadIdx.x) >> 6;
    int lane = threadIdx.x & 63;
    if (wid >= N) return;
    int beg = row_ptr[wid], end = row_ptr[wid + 1];
    float adv = ad1[wid];

    float wsum = 0.f, acc = 0.f;
    for (int chunk = beg; chunk < end; chunk += 64) {
        int nv = min(64, end - chunk);
        int s_l = 0;
        float w_l = 0.f;
        if (lane < nv) {
            s_l = csr[chunk + lane];
            w_l = __expf(lrelu(as1[s_l] + adv));
        }
        wsum += w_l;
        for (int j = 0; j < nv; j++) {
            int s = __shfl(s_l, j);
            float w = __shfl(w_l, j);
            acc += w * __half2float(h2[(size_t)s * 64 + lane]);
        }
    }
#pragma unroll
    for (int off = 32; off; off >>= 1) wsum += __shfl_xor(wsum, off);
    out[(size_t)wid * 64 + lane] = acc / (wsum + 1e-16f) + bias1[lane];
}

extern "C" void kernel_launch(void* const* d_in, const int* in_sizes, int n_in,
                              void* d_out, int out_size, void* d_ws, size_t ws_size,
                              hipStream_t stream) {
    const float* x    = (const float*)d_in[0];
    const int*   ei   = (const int*)d_in[1];
    const float* W0   = (const float*)d_in[2];
    const float* as0w = (const float*)d_in[3];
    const float* ad0w = (const float*)d_in[4];
    const float* b0   = (const float*)d_in[5];
    const float* W1   = (const float*)d_in[6];
    const float* as1w = (const float*)d_in[7];
    const float* ad1w = (const float*)d_in[8];
    const float* b1   = (const float*)d_in[9];
    float* out = (float*)d_out;

    const int HID = in_sizes[9];          // 64
    const int N   = out_size / HID;       // 50000
    const int E   = in_sizes[1] / 2;      // 800000
    const int* src = ei;
    const int* dst = ei + E;

    char* ws = (char*)d_ws;
    size_t off = 0;
    auto alloc = [&](size_t bytes) -> void* {
        off = (off + 255) & ~(size_t)255;
        void* p = ws + off;
        off += bytes;
        return p;
    };
    int*    counts   = (int*)alloc((size_t)N * 4);
    int*    cursor   = (int*)alloc((size_t)N * 4);
    int*    row_ptr  = (int*)alloc((size_t)(N + 1) * 4);
    int*    partials = (int*)alloc(256 * 4);
    int*    csr      = (int*)alloc((size_t)(E + N) * 4);
    float*  Wa       = (float*)alloc(128 * 8 * 4);
    float*  as0      = (float*)alloc((size_t)N * 4 * 4);
    float*  ad0v     = (float*)alloc((size_t)N * 4 * 4);
    __half* xh       = (__half*)alloc((size_t)N * 128 * 2);
    __half* aggx     = (__half*)alloc((size_t)N * 512 * 2);
    __half* h1       = (__half*)alloc((size_t)N * 256 * 2);
    // aliases: dead buffers reused
    __half* h2       = xh;             // xh dead after agg0; N*64 <= N*128 halves
    float*  as1      = as0;            // as0 dead after agg0
    float*  ad1v     = ad0v;

    const int nb = (N + 1023) / 1024;  // <= 256

    hipMemsetAsync(counts, 0, (size_t)N * 4, stream);
    count_kernel<<<2048, 256, 0, stream>>>(dst, E, counts);
    scan1_kernel<<<nb, 256, 0, stream>>>(counts, N, cursor, partials);
    scan2_kernel<<<1, 256, 0, stream>>>(partials, nb, row_ptr + N);
    scan3_kernel<<<nb, 256, 0, stream>>>(partials, N, row_ptr, cursor);
    scatter_kernel<<<2048, 256, 0, stream>>>(src, dst, E, N, cursor, csr);

    prep_wa<<<2, 256, 0, stream>>>(W0, as0w, ad0w, Wa);
    gemv0_kernel<<<(N * 64 + 255) / 256, 256, 0, stream>>>(x, Wa, N, xh, as0, ad0v);
    agg0_kernel<<<(N * 64 + 255) / 256, 256, 0, stream>>>(row_ptr, csr, xh, as0, ad0v, N, aggx);
    dim3 gA((N + 63) / 64, 4);
    gemmA_kernel<<<gA, 256, 0, stream>>>(aggx, W0, b0, N, h1);
    gemmB_kernel<<<(N + 63) / 64, 256, 0, stream>>>(h1, W1, as1w, ad1w, N, h2, as1, ad1v);
    agg1_kernel<<<(N * 64 + 255) / 256, 256, 0, stream>>>(row_ptr, csr, h2, as1, ad1v, b1, N, out);
}

// Round 6
// 303.388 us; speedup vs baseline: 5.1592x; 1.2404x over previous
//
#include <hip/hip_runtime.h>
#include <hip/hip_fp16.h>

#define NEG_SLOPE 0.2f

typedef _Float16 half8 __attribute__((ext_vector_type(8)));
typedef float f32x4 __attribute__((ext_vector_type(4)));

__device__ __forceinline__ float lrelu(float x) { return x > 0.f ? x : NEG_SLOPE * x; }
__device__ __forceinline__ float elu(float x) { return x > 0.f ? x : (__expf(x) - 1.f); }

// ---------------- CSR build ----------------
__global__ void count_kernel(const int* __restrict__ dst, int E, int* __restrict__ counts) {
    int stride = gridDim.x * blockDim.x;
    for (int i = blockIdx.x * blockDim.x + threadIdx.x; i < E; i += stride)
        atomicAdd(&counts[dst[i]], 1);
}

// hierarchical scan of (counts[i]+1), 1024 elements per block
__global__ __launch_bounds__(256) void scan1_kernel(const int* __restrict__ counts, int N,
                                                    int* __restrict__ local, int* __restrict__ partials) {
    __shared__ int lds[256];
    int t = threadIdx.x;
    int base = blockIdx.x * 1024 + t * 4;
    int e[4];
#pragma unroll
    for (int j = 0; j < 4; j++) e[j] = (base + j < N) ? counts[base + j] + 1 : 0;  // +1 = self loop
    int s = e[0] + e[1] + e[2] + e[3];
    lds[t] = s;
    __syncthreads();
    for (int off = 1; off < 256; off <<= 1) {
        int v = (t >= off) ? lds[t - off] : 0;
        __syncthreads();
        lds[t] += v;
        __syncthreads();
    }
    int run = lds[t] - s;   // exclusive prefix within block
    if (t == 255) partials[blockIdx.x] = lds[255];
#pragma unroll
    for (int j = 0; j < 4; j++) {
        if (base + j < N) local[base + j] = run;
        run += e[j];
    }
}

__global__ __launch_bounds__(256) void scan2_kernel(int* __restrict__ partials, int nb,
                                                    int* __restrict__ total) {
    __shared__ int lds[256];
    int t = threadIdx.x;
    int v = (t < nb) ? partials[t] : 0;
    lds[t] = v;
    __syncthreads();
    for (int off = 1; off < 256; off <<= 1) {
        int u = (t >= off) ? lds[t - off] : 0;
        __syncthreads();
        lds[t] += u;
        __syncthreads();
    }
    if (t < nb) partials[t] = lds[t] - v;  // exclusive
    if (t == 255) *total = lds[255];
}

__global__ __launch_bounds__(256) void scan3_kernel(const int* __restrict__ partials, int N,
                                                    int* __restrict__ row_ptr, int* __restrict__ cursor) {
    int base = blockIdx.x * 1024 + threadIdx.x * 4;
    int off = partials[blockIdx.x];
    if (base + 3 < N) {
        int4 v = *(const int4*)(cursor + base);
        v.x += off; v.y += off; v.z += off; v.w += off;
        *(int4*)(row_ptr + base) = v;
        *(int4*)(cursor + base) = v;
    } else {
#pragma unroll
        for (int j = 0; j < 4; j++) {
            int i = base + j;
            if (i < N) { int v = cursor[i] + off; row_ptr[i] = v; cursor[i] = v; }
        }
    }
}

__global__ void scatter_kernel(const int* __restrict__ src, const int* __restrict__ dst,
                               int E, int N, int* __restrict__ cursor, int* __restrict__ csr_src) {
    int stride = gridDim.x * blockDim.x;
    int total = E + N;
    for (int i = blockIdx.x * blockDim.x + threadIdx.x; i < total; i += stride) {
        int s, d;
        if (i < E) { s = src[i]; d = dst[i]; }
        else       { s = i - E;  d = s; }
        csr_src[atomicAdd(&cursor[d], 1)] = s;
    }
}

// ---------------- Wa[k][0..3]=W0@a_src per head, [4..7]=W0@a_dst ----------------
__global__ __launch_bounds__(256) void prep_wa(const float* __restrict__ W0,
                                               const float* __restrict__ a_s, const float* __restrict__ a_d,
                                               float* __restrict__ Wa) {
    int t = blockIdx.x * 256 + threadIdx.x;  // 512 total: k=t>>2, h=t&3
    if (t >= 512) return;
    int k = t >> 2, h = t & 3;
    float ss = 0.f, dd = 0.f;
    for (int c = 0; c < 64; c++) {
        float w = W0[(size_t)k * 256 + h * 64 + c];
        ss += w * a_s[h * 64 + c];
        dd += w * a_d[h * 64 + c];
    }
    Wa[k * 8 + h] = ss;
    Wa[k * 8 + 4 + h] = dd;
}

// ---------------- transposed fp16 weights: Wt0[c][k] (256x128), Wt1[c][k] (64x256) ----------------
__global__ __launch_bounds__(256) void prep_wt(const float* __restrict__ W0, const float* __restrict__ W1,
                                               __half* __restrict__ Wt0, __half* __restrict__ Wt1) {
    int t = blockIdx.x * 256 + threadIdx.x;
    if (t < 256 * 128) {
        int c = t >> 7, k = t & 127;
        Wt0[t] = __float2half_rn(W0[(size_t)k * 256 + c]);
    } else if (t < 256 * 128 + 64 * 256) {
        int i = t - 256 * 128;
        int c = i >> 8, k = i & 255;
        Wt1[i] = __float2half_rn(W1[(size_t)k * 64 + c]);
    }
}

// ---------------- gemv0: as0/ad0 = x @ Wa; also xh = fp16(x). one wave per node ----------------
__global__ __launch_bounds__(256) void gemv0_kernel(const float* __restrict__ x, const float* __restrict__ Wa,
                                                    int N, __half* __restrict__ xh,
                                                    float* __restrict__ as0, float* __restrict__ ad0) {
    int wid = (blockIdx.x * 256 + threadIdx.x) >> 6;
    int lane = threadIdx.x & 63;
    if (wid >= N) return;
    float2 xv = *(const float2*)(x + (size_t)wid * 128 + lane * 2);
    *(__half2*)(xh + (size_t)wid * 128 + lane * 2) = __floats2half2_rn(xv.x, xv.y);
    float p[8];
#pragma unroll
    for (int j = 0; j < 8; j++)
        p[j] = xv.x * Wa[(lane * 2) * 8 + j] + xv.y * Wa[(lane * 2 + 1) * 8 + j];
#pragma unroll
    for (int off = 32; off; off >>= 1)
#pragma unroll
        for (int j = 0; j < 8; j++) p[j] += __shfl_xor(p[j], off);
    if (lane == 0) {
        *(float4*)(as0 + (size_t)wid * 4) = make_float4(p[0], p[1], p[2], p[3]);
        *(float4*)(ad0 + (size_t)wid * 4) = make_float4(p[4], p[5], p[6], p[7]);
    }
}

// ---------------- layer 0 aggregation over x (fp16): aggx[4][N][128] head-major ----------------
__global__ __launch_bounds__(256) void agg0_kernel(
        const int* __restrict__ row_ptr, const int* __restrict__ csr,
        const __half* __restrict__ xh, const float* __restrict__ as0, const float* __restrict__ ad0,
        int N, __half* __restrict__ aggx) {
    int wid = (blockIdx.x * 256 + threadIdx.x) >> 6;
    int lane = threadIdx.x & 63;
    if (wid >= N) return;
    int beg = row_ptr[wid], end = row_ptr[wid + 1];
    float4 adv = *(const float4*)(ad0 + (size_t)wid * 4);

    float wsum[4] = {0.f, 0.f, 0.f, 0.f};
    float acc[4][2] = {};
    for (int chunk = beg; chunk < end; chunk += 64) {
        int nv = min(64, end - chunk);
        int s_l = 0;
        float4 w4 = make_float4(0.f, 0.f, 0.f, 0.f);
        if (lane < nv) {
            s_l = csr[chunk + lane];
            float4 asv = *(const float4*)(as0 + (size_t)s_l * 4);
            w4.x = __expf(lrelu(asv.x + adv.x));
            w4.y = __expf(lrelu(asv.y + adv.y));
            w4.z = __expf(lrelu(asv.z + adv.z));
            w4.w = __expf(lrelu(asv.w + adv.w));
        }
        wsum[0] += w4.x; wsum[1] += w4.y; wsum[2] += w4.z; wsum[3] += w4.w;
        for (int j = 0; j < nv; j++) {
            int s = __shfl(s_l, j);
            float wx = __shfl(w4.x, j);
            float wy = __shfl(w4.y, j);
            float wz = __shfl(w4.z, j);
            float ww = __shfl(w4.w, j);
            float2 f = __half22float2(*(const __half2*)(xh + (size_t)s * 128 + lane * 2));
            acc[0][0] += wx * f.x; acc[0][1] += wx * f.y;
            acc[1][0] += wy * f.x; acc[1][1] += wy * f.y;
            acc[2][0] += wz * f.x; acc[2][1] += wz * f.y;
            acc[3][0] += ww * f.x; acc[3][1] += ww * f.y;
        }
    }
#pragma unroll
    for (int off = 32; off; off >>= 1)
#pragma unroll
        for (int h = 0; h < 4; h++) wsum[h] += __shfl_xor(wsum[h], off);
#pragma unroll
    for (int h = 0; h < 4; h++) {
        float inv = 1.f / (wsum[h] + 1e-16f);
        *(__half2*)(aggx + ((size_t)h * N + wid) * 128 + lane * 2) =
            __floats2half2_rn(acc[h][0] * inv, acc[h][1] * inv);
    }
}

// ---------------- gemmA (MFMA): h1 = ELU(aggx_head @ W0_head + b0) ----------------
// block: 256 thr = 4 waves; 64x64 tile; wave w: rows 16w..16w+15, all 64 cols; K=128 in one stage.
// LDS padded to 136 halves/row (272B): fragment reads 2-way bank-aliased (free).
__global__ __launch_bounds__(256) void gemmA_kernel(
        const __half* __restrict__ aggx, const __half* __restrict__ Wt0,
        const float* __restrict__ bias0, int N, __half* __restrict__ h1) {
    __shared__ __half As[64][136];
    __shared__ __half Bs[64][136];
    const int head = blockIdx.y;
    const int block_row = blockIdx.x * 64;
    const int t = threadIdx.x;
    const __half* A = aggx + (size_t)head * N * 128;

#pragma unroll
    for (int ii = 0; ii < 4; ii++) {
        int i = t + ii * 256;
        int r = i >> 4, c4 = i & 15;
        int gr = block_row + r;
        uint4 av = make_uint4(0, 0, 0, 0);
        if (gr < N) av = *(const uint4*)(A + (size_t)gr * 128 + c4 * 8);
        *(uint4*)&As[r][c4 * 8] = av;
        *(uint4*)&Bs[r][c4 * 8] = *(const uint4*)(Wt0 + ((size_t)head * 64 + r) * 128 + c4 * 8);
    }
    __syncthreads();

    const int w = t >> 6, l15 = t & 15, l4 = (t & 63) >> 4;
    f32x4 acc[4];
#pragma unroll
    for (int ct = 0; ct < 4; ct++) acc[ct] = (f32x4){0.f, 0.f, 0.f, 0.f};
#pragma unroll
    for (int kk = 0; kk < 4; kk++) {
        half8 a = *(const half8*)&As[w * 16 + l15][kk * 32 + l4 * 8];
#pragma unroll
        for (int ct = 0; ct < 4; ct++) {
            half8 b = *(const half8*)&Bs[ct * 16 + l15][kk * 32 + l4 * 8];
            acc[ct] = __builtin_amdgcn_mfma_f32_16x16x32_f16(a, b, acc[ct], 0, 0, 0);
        }
    }
#pragma unroll
    for (int ct = 0; ct < 4; ct++) {
        int col = head * 64 + ct * 16 + l15;
        float bv = bias0[col];
#pragma unroll
        for (int reg = 0; reg < 4; reg++) {
            int row = block_row + w * 16 + l4 * 4 + reg;
            if (row < N) h1[(size_t)row * 256 + col] = __float2half_rn(elu(acc[ct][reg] + bv));
        }
    }
}

// ---------------- gemmB (MFMA): h2 = h1 @ W1 + fused alpha1 dots; K=256 in 2 chunks ----------------
__global__ __launch_bounds__(256) void gemmB_kernel(
        const __half* __restrict__ h1, const __half* __restrict__ Wt1,
        const float* __restrict__ a_s, const float* __restrict__ a_d,
        int N, __half* __restrict__ h2, float* __restrict__ as1, float* __restrict__ ad1) {
    __shared__ __half As[64][136];
    __shared__ __half Bs[64][136];
    const int block_row = blockIdx.x * 64;
    const int t = threadIdx.x;
    const int w = t >> 6, l15 = t & 15, l4 = (t & 63) >> 4;
    f32x4 acc[4];
#pragma unroll
    for (int ct = 0; ct < 4; ct++) acc[ct] = (f32x4){0.f, 0.f, 0.f, 0.f};

    for (int kc = 0; kc < 2; kc++) {
        __syncthreads();
#pragma unroll
        for (int ii = 0; ii < 4; ii++) {
            int i = t + ii * 256;
            int r = i >> 4, c4 = i & 15;
            int gr = block_row + r;
            uint4 av = make_uint4(0, 0, 0, 0);
            if (gr < N) av = *(const uint4*)(h1 + (size_t)gr * 256 + kc * 128 + c4 * 8);
            *(uint4*)&As[r][c4 * 8] = av;
            *(uint4*)&Bs[r][c4 * 8] = *(const uint4*)(Wt1 + (size_t)r * 256 + kc * 128 + c4 * 8);
        }
        __syncthreads();
#pragma unroll
        for (int kk = 0; kk < 4; kk++) {
            half8 a = *(const half8*)&As[w * 16 + l15][kk * 32 + l4 * 8];
#pragma unroll
            for (int ct = 0; ct < 4; ct++) {
                half8 b = *(const half8*)&Bs[ct * 16 + l15][kk * 32 + l4 * 8];
                acc[ct] = __builtin_amdgcn_mfma_f32_16x16x32_f16(a, b, acc[ct], 0, 0, 0);
            }
        }
    }

    float asv[4], adv[4];
#pragma unroll
    for (int ct = 0; ct < 4; ct++) { asv[ct] = a_s[ct * 16 + l15]; adv[ct] = a_d[ct * 16 + l15]; }
#pragma unroll
    for (int reg = 0; reg < 4; reg++) {
        float sd = 0.f, dd = 0.f;
#pragma unroll
        for (int ct = 0; ct < 4; ct++) { sd += acc[ct][reg] * asv[ct]; dd += acc[ct][reg] * adv[ct]; }
#pragma unroll
        for (int off = 1; off < 16; off <<= 1) { sd += __shfl_xor(sd, off); dd += __shfl_xor(dd, off); }
        int row = block_row + w * 16 + l4 * 4 + reg;
        if (row < N) {
#pragma unroll
            for (int ct = 0; ct < 4; ct++)
                h2[(size_t)row * 64 + ct * 16 + l15] = __float2half_rn(acc[ct][reg]);
            if (l15 == 0) { as1[row] = sd; ad1[row] = dd; }
        }
    }
}

// ---------------- layer 1 aggregation (H=1, C=64): one wave per node, single pass ----------------
__global__ __launch_bounds__(256) void agg1_kernel(
        const int* __restrict__ row_ptr, const int* __restrict__ csr,
        const __half* __restrict__ h2, const float* __restrict__ as1, const float* __restrict__ ad1,
        const float* __restrict__ bias1, int N, float* __restrict__ out) {
    int wid = (blockIdx.x * 256 + threadIdx.x) >> 6;
    int lane = threadIdx.x & 63;
    if (wid >= N) return;
    int beg = row_ptr[wid], end = row_ptr[wid + 1];
    float adv = ad1[wid];

    float wsum = 0.f, acc = 0.f;
    for (int chunk = beg; chunk < end; chunk += 64) {
        int nv = min(64, end - chunk);
        int s_l = 0;
        float w_l = 0.f;
        if (lane < nv) {
            s_l = csr[chunk + lane];
            w_l = __expf(lrelu(as1[s_l] + adv));
        }
        wsum += w_l;
        for (int j = 0; j < nv; j++) {
            int s = __shfl(s_l, j);
            float w = __shfl(w_l, j);
            acc += w * __half2float(h2[(size_t)s * 64 + lane]);
        }
    }
#pragma unroll
    for (int off = 32; off; off >>= 1) wsum += __shfl_xor(wsum, off);
    out[(size_t)wid * 64 + lane] = acc / (wsum + 1e-16f) + bias1[lane];
}

extern "C" void kernel_launch(void* const* d_in, const int* in_sizes, int n_in,
                              void* d_out, int out_size, void* d_ws, size_t ws_size,
                              hipStream_t stream) {
    const float* x    = (const float*)d_in[0];
    const int*   ei   = (const int*)d_in[1];
    const float* W0   = (const float*)d_in[2];
    const float* as0w = (const float*)d_in[3];
    const float* ad0w = (const float*)d_in[4];
    const float* b0   = (const float*)d_in[5];
    const float* W1   = (const float*)d_in[6];
    const float* as1w = (const float*)d_in[7];
    const float* ad1w = (const float*)d_in[8];
    const float* b1   = (const float*)d_in[9];
    float* out = (float*)d_out;

    const int HID = in_sizes[9];          // 64
    const int N   = out_size / HID;       // 50000
    const int E   = in_sizes[1] / 2;      // 800000
    const int* src = ei;
    const int* dst = ei + E;

    char* ws = (char*)d_ws;
    size_t off = 0;
    auto alloc = [&](size_t bytes) -> void* {
        off = (off + 255) & ~(size_t)255;
        void* p = ws + off;
        off += bytes;
        return p;
    };
    int*    counts   = (int*)alloc((size_t)N * 4);
    int*    cursor   = (int*)alloc((size_t)N * 4);
    int*    row_ptr  = (int*)alloc((size_t)(N + 1) * 4);
    int*    partials = (int*)alloc(256 * 4);
    int*    csr      = (int*)alloc((size_t)(E + N) * 4);
    float*  Wa       = (float*)alloc(128 * 8 * 4);
    __half* Wt0      = (__half*)alloc(256 * 128 * 2);
    __half* Wt1      = (__half*)alloc(64 * 256 * 2);
    float*  as0      = (float*)alloc((size_t)N * 4 * 4);
    float*  ad0v     = (float*)alloc((size_t)N * 4 * 4);
    __half* xh       = (__half*)alloc((size_t)N * 128 * 2);
    __half* aggx     = (__half*)alloc((size_t)N * 512 * 2);   // [4][N][128]
    __half* h1       = (__half*)alloc((size_t)N * 256 * 2);
    // aliases: dead buffers reused
    __half* h2       = xh;             // xh dead after agg0; N*64 <= N*128 halves
    float*  as1      = as0;            // as0 dead after agg0
    float*  ad1v     = ad0v;

    const int nb = (N + 1023) / 1024;  // <= 256

    hipMemsetAsync(counts, 0, (size_t)N * 4, stream);
    count_kernel<<<2048, 256, 0, stream>>>(dst, E, counts);
    scan1_kernel<<<nb, 256, 0, stream>>>(counts, N, cursor, partials);
    scan2_kernel<<<1, 256, 0, stream>>>(partials, nb, row_ptr + N);
    scan3_kernel<<<nb, 256, 0, stream>>>(partials, N, row_ptr, cursor);
    scatter_kernel<<<2048, 256, 0, stream>>>(src, dst, E, N, cursor, csr);

    prep_wa<<<2, 256, 0, stream>>>(W0, as0w, ad0w, Wa);
    prep_wt<<<192, 256, 0, stream>>>(W0, W1, Wt0, Wt1);
    gemv0_kernel<<<(N * 64 + 255) / 256, 256, 0, stream>>>(x, Wa, N, xh, as0, ad0v);
    agg0_kernel<<<(N * 64 + 255) / 256, 256, 0, stream>>>(row_ptr, csr, xh, as0, ad0v, N, aggx);
    dim3 gA((N + 63) / 64, 4);
    gemmA_kernel<<<gA, 256, 0, stream>>>(aggx, Wt0, b0, N, h1);
    gemmB_kernel<<<(N + 63) / 64, 256, 0, stream>>>(h1, Wt1, as1w, ad1w, N, h2, as1, ad1v);
    agg1_kernel<<<(N * 64 + 255) / 256, 256, 0, stream>>>(row_ptr, csr, h2, as1, ad1v, b1, N, out);
}